// Round 8
// baseline (335.165 us; speedup 1.0000x reference)
//
#include <hip/hip_runtime.h>
#include <hip/hip_bf16.h>

// Problem: B=4, L=2048, C=1024, H=16, D=64, M=B*L=8192. I/O f32.
// Internal: bf16 MFMA, f32 accumulate. Verified absmax 9.8e-4 (thr 4.04e-3).
// R8: q pre-scaled by scale*log2e (no per-score FMA; shift dropped — softmax
//     ratio is shift-invariant, |arg|<=5.8 at scale=4; uniform fallback branch
//     for scale>=30), split S-chains; GEMMs moved to 32x32x16 MFMA.

typedef __attribute__((ext_vector_type(8))) short bf16x8;
typedef __attribute__((ext_vector_type(16))) float f32x16;

#define MAXLOG 4.60517018598809f   // ln(100)
#define LOG2E  1.4426950408889634f

__device__ __forceinline__ float bf2f(unsigned short u) {
    union { unsigned int i; float f; } v; v.i = ((unsigned int)u) << 16; return v.f;
}
__device__ __forceinline__ unsigned short f2bf(float f) {
    union { float f; unsigned int i; } v; v.f = f;
    unsigned int x = v.i;
    return (unsigned short)((x + 0x7FFFu + ((x >> 16) & 1u)) >> 16);  // RNE
}
__device__ __forceinline__ unsigned fbits(float f) {
    union { float f; unsigned u; } v; v.f = f; return v.u;
}
__device__ __forceinline__ bf16x8 pack8(const float* __restrict__ p) {
    float4 a = *(const float4*)p;
    float4 b = *(const float4*)(p + 4);
    bf16x8 r;
    r[0] = (short)f2bf(a.x); r[1] = (short)f2bf(a.y);
    r[2] = (short)f2bf(a.z); r[3] = (short)f2bf(a.w);
    r[4] = (short)f2bf(b.x); r[5] = (short)f2bf(b.y);
    r[6] = (short)f2bf(b.z); r[7] = (short)f2bf(b.w);
    return r;
}
__device__ __forceinline__ void gload_lds16(const void* g, void* l) {
    __builtin_amdgcn_global_load_lds((const __attribute__((address_space(1))) void*)g,
                                     (__attribute__((address_space(3))) void*)l, 16, 0, 0);
}

// ---------------------------------------- fused prep: casts + bias (1 kernel)
__global__ __launch_bounds__(256) void k_prep(
    const float* __restrict__ x, const float* __restrict__ Wqkv,
    const float* __restrict__ Wp, const float* __restrict__ qbia,
    const float* __restrict__ vbia,
    unsigned short* __restrict__ xb, unsigned short* __restrict__ Wqkvb,
    unsigned short* __restrict__ Wpb, float* __restrict__ bias3)
{
    int i = blockIdx.x * 256 + threadIdx.x;
    if (i < 1048576) {
        *(bf16x8*)&xb[(long)i * 8] = pack8(&x[(long)i * 8]);
    } else if (i < 1441792) {
        int j = i - 1048576;
        *(bf16x8*)&Wqkvb[(long)j * 8] = pack8(&Wqkv[(long)j * 8]);
    } else if (i < 1572864) {
        int j = i - 1441792;
        *(bf16x8*)&Wpb[(long)j * 8] = pack8(&Wp[(long)j * 8]);
    } else if (i < 1573248) {
        int j = (i - 1572864) * 8;
        for (int u = 0; u < 8; ++u) {
            int n = j + u;
            float v = 0.0f;
            if (n < 1024) v = qbia[n];
            else if (n >= 2048) v = vbia[n - 2048];
            bias3[n] = v;
        }
    }
}

// ------------------------- GEMM, B^T input, 32x32x16 MFMA, global_load_lds
// C[m][n] = sum_k A[m][k]*B[n][k] + bias[n]. 128x128 tile, 4 waves, each
// wave a 64x64 patch as 2x2 grid of 32x32 tiles.
template<bool OUT_F32>
__global__ __launch_bounds__(256) void k_gemm_lds(
    const unsigned short* __restrict__ A, const unsigned short* __restrict__ Bh,
    const float* __restrict__ bias, void* __restrict__ Cp, int N, int K)
{
    __shared__ unsigned short As[128 * 32];
    __shared__ unsigned short Bs[128 * 32];
    const int t = threadIdx.x, wave = t >> 6, lane = t & 63;
    const int m32 = lane & 31, half = lane >> 5;
    const int bm = blockIdx.x * 128, bn = blockIdx.y * 128;
    const int wr = (wave >> 1) * 64, wc = (wave & 1) * 64;
    f32x16 acc[2][2] = {};

    const int srow = lane >> 2;        // 0..15
    const int scol = (lane & 3) * 8;
    const int c0 = wave * 2, c1 = wave * 2 + 1;
    const long ga0 = (long)(bm + c0 * 16 + srow) * K + scol;
    const long ga1 = (long)(bm + c1 * 16 + srow) * K + scol;
    const long gb0 = (long)(bn + c0 * 16 + srow) * K + scol;
    const long gb1 = (long)(bn + c1 * 16 + srow) * K + scol;

    for (int kt = 0; kt < K; kt += 32) {
        __syncthreads();
        gload_lds16(&A[ga0 + kt], &As[c0 * 512]);
        gload_lds16(&A[ga1 + kt], &As[c1 * 512]);
        gload_lds16(&Bh[gb0 + kt], &Bs[c0 * 512]);
        gload_lds16(&Bh[gb1 + kt], &Bs[c1 * 512]);
        __syncthreads();
        bf16x8 af[2][2], bfr[2][2];
        for (int mt = 0; mt < 2; ++mt)
            for (int f = 0; f < 2; ++f)
                af[mt][f] = *(const bf16x8*)&As[(wr + mt * 32 + m32) * 32 + f * 16 + half * 8];
        for (int nt = 0; nt < 2; ++nt)
            for (int f = 0; f < 2; ++f)
                bfr[nt][f] = *(const bf16x8*)&Bs[(wc + nt * 32 + m32) * 32 + f * 16 + half * 8];
        for (int f = 0; f < 2; ++f)
            for (int mt = 0; mt < 2; ++mt)
                for (int nt = 0; nt < 2; ++nt)
                    acc[mt][nt] = __builtin_amdgcn_mfma_f32_32x32x16_bf16(
                        af[mt][f], bfr[nt][f], acc[mt][nt], 0, 0, 0);
    }
    // epilogue: 32x32 C/D layout col=lane&31, row=(r&3)+8*(r>>2)+4*half
    for (int mt = 0; mt < 2; ++mt)
        for (int nt = 0; nt < 2; ++nt) {
            int gn = bn + wc + nt * 32 + m32;
            float bv = bias[gn];
            for (int r = 0; r < 16; ++r) {
                int gm = bm + wr + mt * 32 + (r & 3) + 8 * (r >> 2) + 4 * half;
                float val = acc[mt][nt][r] + bv;
                if (OUT_F32) ((float*)Cp)[(long)gm * N + gn] = val;
                else ((unsigned short*)Cp)[(long)gm * N + gn] = f2bf(val);
            }
        }
}

// ------------------------- fused k L2-normalize + v transpose (one qkv pass)
__global__ __launch_bounds__(256) void k_prep_kv(
    const unsigned short* __restrict__ qkv, unsigned short* __restrict__ kb,
    unsigned short* __restrict__ vT)
{
    __shared__ unsigned short Vsh[64 * 72];
    const int t = threadIdx.x;
    const int bh = blockIdx.y, l0 = blockIdx.x * 64;
    const int h = bh & 15, b = bh >> 4;
    const int ll = t >> 2, c16 = (t & 3) * 16;
    const long rowbase = (long)(b * 2048 + l0 + ll) * 3072;

    {
        bf16x8 k0 = *(const bf16x8*)&qkv[rowbase + 1024 + h * 64 + c16];
        bf16x8 k1 = *(const bf16x8*)&qkv[rowbase + 1024 + h * 64 + c16 + 8];
        float e[16]; float ss = 0.f;
        for (int j = 0; j < 8; ++j) { e[j]     = bf2f((unsigned short)k0[j]); ss += e[j] * e[j]; }
        for (int j = 0; j < 8; ++j) { e[8 + j] = bf2f((unsigned short)k1[j]); ss += e[8 + j] * e[8 + j]; }
        ss += __shfl_xor(ss, 1, 64);
        ss += __shfl_xor(ss, 2, 64);
        float rs = 1.0f / fmaxf(sqrtf(ss), 1e-12f);
        bf16x8 o0, o1;
        for (int j = 0; j < 8; ++j) o0[j] = (short)f2bf(e[j] * rs);
        for (int j = 0; j < 8; ++j) o1[j] = (short)f2bf(e[8 + j] * rs);
        long dst = ((long)bh * 2048 + l0 + ll) * 64 + c16;
        *(bf16x8*)&kb[dst]     = o0;
        *(bf16x8*)&kb[dst + 8] = o1;
    }
    *(bf16x8*)&Vsh[ll * 72 + c16]     = *(const bf16x8*)&qkv[rowbase + 2048 + h * 64 + c16];
    *(bf16x8*)&Vsh[ll * 72 + c16 + 8] = *(const bf16x8*)&qkv[rowbase + 2048 + h * 64 + c16 + 8];
    __syncthreads();
    const int d = t >> 2, ls = (t & 3) * 16;
    unsigned short tmp[16];
    for (int j = 0; j < 16; ++j) tmp[j] = Vsh[(ls + j) * 72 + d];
    long dst = (long)(bh * 64 + d) * 2048 + l0 + ls;
    *(bf16x8*)&vT[dst]     = *(bf16x8*)&tmp[0];
    *(bf16x8*)&vT[dst + 8] = *(bf16x8*)&tmp[8];
}

// ------------------------------------------------------------ flash attention
// 32x32x16 MFMA, S^T form (key-permutation: P stays in registers).
// R8: q pre-scaled by scale*LOG2E (MFMA emits log2-unit scores, no per-score
// FMA); no shift in fast path (ratio-invariant, |arg|<=5.8 at scale=4);
// split S dependency chains; ones-MFMA rowsum; double-buffered K/V LDS.
__global__ __launch_bounds__(256, 4) void k_attn32(
    const unsigned short* __restrict__ qkv, const unsigned short* __restrict__ kb,
    const unsigned short* __restrict__ vT, const float* __restrict__ sml,
    unsigned short* __restrict__ attn)
{
    __shared__ unsigned short Ks[2][64 * 72];
    __shared__ unsigned short Vs[2][64 * 72];
    const int t = threadIdx.x, wave = t >> 6, lane = t & 63;
    const int m32 = lane & 31, half = lane >> 5;
    const int bh = blockIdx.y, h = bh & 15, b = bh >> 4;
    const int q0 = blockIdx.x * 128 + wave * 32;
    const float scale = __expf(fminf(sml[h], MAXLOG));
    const float c2 = scale * LOG2E;   // shift for the (rare) large-scale path

    // permuted physical key row for the S^T A-frag (swap quads 1<->2, 5<->6)
    const int qd = m32 >> 2, lo = qd & 3;
    const int prow = ((((lo == 1) || (lo == 2)) ? (qd ^ 3) : qd) << 2) | (m32 & 3);

    // fused q load + L2-normalize; scale folded with LOG2E
    bf16x8 aq[4];
    {
        long base = (long)(b * 2048 + q0 + m32) * 3072 + h * 64;
        float e[32]; float ss = 0.f;
        for (int f = 0; f < 4; ++f) {
            aq[f] = *(const bf16x8*)&qkv[base + f * 16 + half * 8];
            for (int j = 0; j < 8; ++j) { float x = bf2f((unsigned short)aq[f][j]); e[f * 8 + j] = x; ss += x * x; }
        }
        ss += __shfl_xor(ss, 32, 64);
        float rs = (scale * LOG2E) / fmaxf(sqrtf(ss), 1e-12f);
        for (int f = 0; f < 4; ++f)
            for (int j = 0; j < 8; ++j) aq[f][j] = (short)f2bf(e[f * 8 + j] * rs);
    }

    f32x16 o0 = {}, o1 = {}, lacc = {};
    bf16x8 ones; for (int i = 0; i < 8; ++i) ones[i] = (short)0x3F80;
    const int sr = t >> 2, sc = (t & 3) * 16;
    const long kbase = (long)bh * 2048 * 64;
    const long vbase = (long)bh * 64 * 2048;

#define LOADT(kt) \
    kpA = *(const bf16x8*)&kb[kbase + (long)((kt) + sr) * 64 + sc];      \
    kpB = *(const bf16x8*)&kb[kbase + (long)((kt) + sr) * 64 + sc + 8];  \
    vpA = *(const bf16x8*)&vT[vbase + (long)sr * 2048 + (kt) + sc];      \
    vpB = *(const bf16x8*)&vT[vbase + (long)sr * 2048 + (kt) + sc + 8];

#define STORET(buf) \
    *(bf16x8*)&Ks[buf][sr * 72 + sc]     = kpA;  \
    *(bf16x8*)&Ks[buf][sr * 72 + sc + 8] = kpB;  \
    *(bf16x8*)&Vs[buf][sr * 72 + sc]     = vpA;  \
    *(bf16x8*)&Vs[buf][sr * 72 + sc + 8] = vpB;

#define ATTN_STEP(KS, VS, SUB) \
    for (int ktile = 0; ktile < 2; ++ktile) {                                              \
        const unsigned short* krow = &KS[(ktile * 32 + prow) * 72 + half * 8];             \
        bf16x8 bk0 = *(const bf16x8*)&krow[0];                                             \
        bf16x8 bk1 = *(const bf16x8*)&krow[16];                                            \
        bf16x8 bk2 = *(const bf16x8*)&krow[32];                                            \
        bf16x8 bk3 = *(const bf16x8*)&krow[48];                                            \
        f32x16 sa = {}, sb = {};                                                           \
        sa = __builtin_amdgcn_mfma_f32_32x32x16_bf16(bk0, aq[0], sa, 0, 0, 0);             \
        sb = __builtin_amdgcn_mfma_f32_32x32x16_bf16(bk2, aq[2], sb, 0, 0, 0);             \
        sa = __builtin_amdgcn_mfma_f32_32x32x16_bf16(bk1, aq[1], sa, 0, 0, 0);             \
        sb = __builtin_amdgcn_mfma_f32_32x32x16_bf16(bk3, aq[3], sb, 0, 0, 0);             \
        unsigned pu[16];                                                                   \
        for (int j = 0; j < 16; ++j)                                                       \
            pu[j] = fbits(__builtin_amdgcn_exp2f(sa[j] + sb[j] - (SUB)));                  \
        uint4 a0u, a1u;                                                                    \
        a0u.x = __builtin_amdgcn_perm(pu[1],  pu[0],  0x07060302u);                        \
        a0u.y = __builtin_amdgcn_perm(pu[3],  pu[2],  0x07060302u);                        \
        a0u.z = __builtin_amdgcn_perm(pu[5],  pu[4],  0x07060302u);                        \
        a0u.w = __builtin_amdgcn_perm(pu[7],  pu[6],  0x07060302u);                        \
        a1u.x = __builtin_amdgcn_perm(pu[9],  pu[8],  0x07060302u);                        \
        a1u.y = __builtin_amdgcn_perm(pu[11], pu[10], 0x07060302u);                        \
        a1u.z = __builtin_amdgcn_perm(pu[13], pu[12], 0x07060302u);                        \
        a1u.w = __builtin_amdgcn_perm(pu[15], pu[14], 0x07060302u);                        \
        bf16x8 ap0, ap1;                                                                   \
        __builtin_memcpy(&ap0, &a0u, 16); __builtin_memcpy(&ap1, &a1u, 16);                \
        for (int c = 0; c < 2; ++c) {                                                      \
            bf16x8 apc = c ? ap1 : ap0;                                                    \
            bf16x8 bv0 = *(const bf16x8*)&VS[m32 * 72        + ktile * 32 + c * 16 + half * 8]; \
            bf16x8 bv1 = *(const bf16x8*)&VS[(32 + m32) * 72 + ktile * 32 + c * 16 + half * 8]; \
            o0   = __builtin_amdgcn_mfma_f32_32x32x16_bf16(apc, bv0, o0, 0, 0, 0);         \
            o1   = __builtin_amdgcn_mfma_f32_32x32x16_bf16(apc, bv1, o1, 0, 0, 0);         \
            lacc = __builtin_amdgcn_mfma_f32_32x32x16_bf16(apc, ones, lacc, 0, 0, 0);      \
        }                                                                                  \
    }

#define KLOOP(SUB) \
    for (int kt = 0; kt < 2048; kt += 128) {                 \
        LOADT(kt + 64)                                       \
        ATTN_STEP(Ks[0], Vs[0], SUB)                         \
        STORET(1)                                            \
        __syncthreads();                                     \
        const bool more = (kt + 128) < 2048;                 \
        if (more) { LOADT(kt + 128) }                        \
        ATTN_STEP(Ks[1], Vs[1], SUB)                         \
        if (more) {                                          \
            STORET(0)                                        \
            __syncthreads();                                 \
        }                                                    \
    }

    bf16x8 kpA, kpB, vpA, vpB;
    LOADT(0)
    STORET(0)
    __syncthreads();

    if (c2 < 30.0f) {      // wave-uniform; scale=4 here => fast path
        KLOOP(0.0f)        // x - 0.0f folds away: no per-score VALU shift
    } else {
        KLOOP(c2)          // overflow-safe general path
    }
#undef LOADT
#undef STORET
#undef ATTN_STEP
#undef KLOOP

    // epilogue: divide by rowsum (lacc reg r matches o reg r), write attn[B,L,C]
    for (int r = 0; r < 16; ++r) {
        int m = (r & 3) + 8 * (r >> 2) + 4 * half;
        float inv = 1.0f / lacc[r];
        long dst = (long)(b * 2048 + q0 + m) * 1024 + h * 64;
        attn[dst + m32]      = f2bf(o0[r] * inv);
        attn[dst + 32 + m32] = f2bf(o1[r] * inv);
    }
}

// ---------------------------------------------------------------------------
extern "C" void kernel_launch(void* const* d_in, const int* in_sizes, int n_in,
                              void* d_out, int out_size, void* d_ws, size_t ws_size,
                              hipStream_t stream) {
    const float* x    = (const float*)d_in[0];
    const float* Wqkv = (const float*)d_in[1];
    const float* qbia = (const float*)d_in[2];
    const float* vbia = (const float*)d_in[3];
    const float* sml  = (const float*)d_in[4];
    const float* Wp   = (const float*)d_in[5];
    const float* bp   = (const float*)d_in[6];

    char* ws = (char*)d_ws;
    unsigned short* qkv   = (unsigned short*)ws;                    // [0, 50.33MB)
    unsigned short* kbuf  = (unsigned short*)(ws + 50331648);       // hosts Wqkvb first
    unsigned short* Wqkvb = kbuf;
    unsigned short* vT    = (unsigned short*)(ws + 67108864);       // hosts xb first
    unsigned short* xb    = vT;
    unsigned short* attnb = (unsigned short*)(ws + 83886080);
    float*          bias3 = (float*)(ws + 100663296);               // 12KB
    unsigned short* Wpb   = (unsigned short*)(ws + 100679680);      // 2MB
    float*          out   = (float*)d_out;

    hipLaunchKernelGGL(k_prep, dim3(6146), dim3(256), 0, stream,
                       x, Wqkv, Wp, qbia, vbia, xb, Wqkvb, Wpb, bias3);
    hipLaunchKernelGGL((k_gemm_lds<false>), dim3(64, 24), dim3(256), 0, stream,
                       xb, Wqkvb, bias3, (void*)qkv, 3072, 1024);
    hipLaunchKernelGGL(k_prep_kv, dim3(32, 64), dim3(256), 0, stream, qkv, kbuf, vT);
    hipLaunchKernelGGL(k_attn32, dim3(16, 64), dim3(256), 0, stream, qkv, kbuf, vT, sml, attnb);
    hipLaunchKernelGGL((k_gemm_lds<true>), dim3(64, 8), dim3(256), 0, stream,
                       attnb, Wpb, bp, (void*)out, 1024, 1024);
}

// Round 9
// 286.633 us; speedup vs baseline: 1.1693x; 1.1693x over previous
//
#include <hip/hip_runtime.h>
#include <hip/hip_bf16.h>

// Problem: B=4, L=2048, C=1024, H=16, D=64, M=B*L=8192. I/O f32.
// Internal: bf16 MFMA, f32 accumulate. Verified absmax 9.8e-4 (thr 4.04e-3).
// R9: revert R8's S-chain split (caused scratch spill: FETCH 139->258MB at
//     the (256,4) 128-VGPR cliff). Keep q pre-scale by scale*log2e (no
//     per-score FMA) and the 32x32x16 GEMMs (R8's non-attn win).

typedef __attribute__((ext_vector_type(8))) short bf16x8;
typedef __attribute__((ext_vector_type(16))) float f32x16;

#define MAXLOG 4.60517018598809f   // ln(100)
#define LOG2E  1.4426950408889634f

__device__ __forceinline__ float bf2f(unsigned short u) {
    union { unsigned int i; float f; } v; v.i = ((unsigned int)u) << 16; return v.f;
}
__device__ __forceinline__ unsigned short f2bf(float f) {
    union { float f; unsigned int i; } v; v.f = f;
    unsigned int x = v.i;
    return (unsigned short)((x + 0x7FFFu + ((x >> 16) & 1u)) >> 16);  // RNE
}
__device__ __forceinline__ unsigned fbits(float f) {
    union { float f; unsigned u; } v; v.f = f; return v.u;
}
__device__ __forceinline__ bf16x8 pack8(const float* __restrict__ p) {
    float4 a = *(const float4*)p;
    float4 b = *(const float4*)(p + 4);
    bf16x8 r;
    r[0] = (short)f2bf(a.x); r[1] = (short)f2bf(a.y);
    r[2] = (short)f2bf(a.z); r[3] = (short)f2bf(a.w);
    r[4] = (short)f2bf(b.x); r[5] = (short)f2bf(b.y);
    r[6] = (short)f2bf(b.z); r[7] = (short)f2bf(b.w);
    return r;
}
__device__ __forceinline__ void gload_lds16(const void* g, void* l) {
    __builtin_amdgcn_global_load_lds((const __attribute__((address_space(1))) void*)g,
                                     (__attribute__((address_space(3))) void*)l, 16, 0, 0);
}

// ---------------------------------------- fused prep: casts + bias (1 kernel)
__global__ __launch_bounds__(256) void k_prep(
    const float* __restrict__ x, const float* __restrict__ Wqkv,
    const float* __restrict__ Wp, const float* __restrict__ qbia,
    const float* __restrict__ vbia,
    unsigned short* __restrict__ xb, unsigned short* __restrict__ Wqkvb,
    unsigned short* __restrict__ Wpb, float* __restrict__ bias3)
{
    int i = blockIdx.x * 256 + threadIdx.x;
    if (i < 1048576) {
        *(bf16x8*)&xb[(long)i * 8] = pack8(&x[(long)i * 8]);
    } else if (i < 1441792) {
        int j = i - 1048576;
        *(bf16x8*)&Wqkvb[(long)j * 8] = pack8(&Wqkv[(long)j * 8]);
    } else if (i < 1572864) {
        int j = i - 1441792;
        *(bf16x8*)&Wpb[(long)j * 8] = pack8(&Wp[(long)j * 8]);
    } else if (i < 1573248) {
        int j = (i - 1572864) * 8;
        for (int u = 0; u < 8; ++u) {
            int n = j + u;
            float v = 0.0f;
            if (n < 1024) v = qbia[n];
            else if (n >= 2048) v = vbia[n - 2048];
            bias3[n] = v;
        }
    }
}

// ------------------------- GEMM, B^T input, 32x32x16 MFMA, global_load_lds
template<bool OUT_F32>
__global__ __launch_bounds__(256) void k_gemm_lds(
    const unsigned short* __restrict__ A, const unsigned short* __restrict__ Bh,
    const float* __restrict__ bias, void* __restrict__ Cp, int N, int K)
{
    __shared__ unsigned short As[128 * 32];
    __shared__ unsigned short Bs[128 * 32];
    const int t = threadIdx.x, wave = t >> 6, lane = t & 63;
    const int m32 = lane & 31, half = lane >> 5;
    const int bm = blockIdx.x * 128, bn = blockIdx.y * 128;
    const int wr = (wave >> 1) * 64, wc = (wave & 1) * 64;
    f32x16 acc[2][2] = {};

    const int srow = lane >> 2;        // 0..15
    const int scol = (lane & 3) * 8;
    const int c0 = wave * 2, c1 = wave * 2 + 1;
    const long ga0 = (long)(bm + c0 * 16 + srow) * K + scol;
    const long ga1 = (long)(bm + c1 * 16 + srow) * K + scol;
    const long gb0 = (long)(bn + c0 * 16 + srow) * K + scol;
    const long gb1 = (long)(bn + c1 * 16 + srow) * K + scol;

    for (int kt = 0; kt < K; kt += 32) {
        __syncthreads();
        gload_lds16(&A[ga0 + kt], &As[c0 * 512]);
        gload_lds16(&A[ga1 + kt], &As[c1 * 512]);
        gload_lds16(&Bh[gb0 + kt], &Bs[c0 * 512]);
        gload_lds16(&Bh[gb1 + kt], &Bs[c1 * 512]);
        __syncthreads();
        bf16x8 af[2][2], bfr[2][2];
        for (int mt = 0; mt < 2; ++mt)
            for (int f = 0; f < 2; ++f)
                af[mt][f] = *(const bf16x8*)&As[(wr + mt * 32 + m32) * 32 + f * 16 + half * 8];
        for (int nt = 0; nt < 2; ++nt)
            for (int f = 0; f < 2; ++f)
                bfr[nt][f] = *(const bf16x8*)&Bs[(wc + nt * 32 + m32) * 32 + f * 16 + half * 8];
        for (int f = 0; f < 2; ++f)
            for (int mt = 0; mt < 2; ++mt)
                for (int nt = 0; nt < 2; ++nt)
                    acc[mt][nt] = __builtin_amdgcn_mfma_f32_32x32x16_bf16(
                        af[mt][f], bfr[nt][f], acc[mt][nt], 0, 0, 0);
    }
    // epilogue: 32x32 C/D layout col=lane&31, row=(r&3)+8*(r>>2)+4*half
    for (int mt = 0; mt < 2; ++mt)
        for (int nt = 0; nt < 2; ++nt) {
            int gn = bn + wc + nt * 32 + m32;
            float bv = bias[gn];
            for (int r = 0; r < 16; ++r) {
                int gm = bm + wr + mt * 32 + (r & 3) + 8 * (r >> 2) + 4 * half;
                float val = acc[mt][nt][r] + bv;
                if (OUT_F32) ((float*)Cp)[(long)gm * N + gn] = val;
                else ((unsigned short*)Cp)[(long)gm * N + gn] = f2bf(val);
            }
        }
}

// ------------------------- fused k L2-normalize + v transpose (one qkv pass)
__global__ __launch_bounds__(256) void k_prep_kv(
    const unsigned short* __restrict__ qkv, unsigned short* __restrict__ kb,
    unsigned short* __restrict__ vT)
{
    __shared__ unsigned short Vsh[64 * 72];
    const int t = threadIdx.x;
    const int bh = blockIdx.y, l0 = blockIdx.x * 64;
    const int h = bh & 15, b = bh >> 4;
    const int ll = t >> 2, c16 = (t & 3) * 16;
    const long rowbase = (long)(b * 2048 + l0 + ll) * 3072;

    {
        bf16x8 k0 = *(const bf16x8*)&qkv[rowbase + 1024 + h * 64 + c16];
        bf16x8 k1 = *(const bf16x8*)&qkv[rowbase + 1024 + h * 64 + c16 + 8];
        float e[16]; float ss = 0.f;
        for (int j = 0; j < 8; ++j) { e[j]     = bf2f((unsigned short)k0[j]); ss += e[j] * e[j]; }
        for (int j = 0; j < 8; ++j) { e[8 + j] = bf2f((unsigned short)k1[j]); ss += e[8 + j] * e[8 + j]; }
        ss += __shfl_xor(ss, 1, 64);
        ss += __shfl_xor(ss, 2, 64);
        float rs = 1.0f / fmaxf(sqrtf(ss), 1e-12f);
        bf16x8 o0, o1;
        for (int j = 0; j < 8; ++j) o0[j] = (short)f2bf(e[j] * rs);
        for (int j = 0; j < 8; ++j) o1[j] = (short)f2bf(e[8 + j] * rs);
        long dst = ((long)bh * 2048 + l0 + ll) * 64 + c16;
        *(bf16x8*)&kb[dst]     = o0;
        *(bf16x8*)&kb[dst + 8] = o1;
    }
    *(bf16x8*)&Vsh[ll * 72 + c16]     = *(const bf16x8*)&qkv[rowbase + 2048 + h * 64 + c16];
    *(bf16x8*)&Vsh[ll * 72 + c16 + 8] = *(const bf16x8*)&qkv[rowbase + 2048 + h * 64 + c16 + 8];
    __syncthreads();
    const int d = t >> 2, ls = (t & 3) * 16;
    unsigned short tmp[16];
    for (int j = 0; j < 16; ++j) tmp[j] = Vsh[(ls + j) * 72 + d];
    long dst = (long)(bh * 64 + d) * 2048 + l0 + ls;
    *(bf16x8*)&vT[dst]     = *(bf16x8*)&tmp[0];
    *(bf16x8*)&vT[dst + 8] = *(bf16x8*)&tmp[8];
}

// ------------------------------------------------------------ flash attention
// 32x32x16 MFMA, S^T form (key-permutation: P stays in registers).
// R9: single S accumulator chain (R7 register footprint — no spill at the
// (256,4) 128-VGPR cliff); q pre-scaled by scale*LOG2E so P = exp2(s) with
// no per-score FMA (fast path; wave-uniform shifted path for scale>=30).
__global__ __launch_bounds__(256, 4) void k_attn32(
    const unsigned short* __restrict__ qkv, const unsigned short* __restrict__ kb,
    const unsigned short* __restrict__ vT, const float* __restrict__ sml,
    unsigned short* __restrict__ attn)
{
    __shared__ unsigned short Ks[2][64 * 72];
    __shared__ unsigned short Vs[2][64 * 72];
    const int t = threadIdx.x, wave = t >> 6, lane = t & 63;
    const int m32 = lane & 31, half = lane >> 5;
    const int bh = blockIdx.y, h = bh & 15, b = bh >> 4;
    const int q0 = blockIdx.x * 128 + wave * 32;
    const float scale = __expf(fminf(sml[h], MAXLOG));
    const float c2 = scale * LOG2E;   // shift for the (rare) large-scale path

    // permuted physical key row for the S^T A-frag (swap quads 1<->2, 5<->6)
    const int qd = m32 >> 2, lo = qd & 3;
    const int prow = ((((lo == 1) || (lo == 2)) ? (qd ^ 3) : qd) << 2) | (m32 & 3);

    // fused q load + L2-normalize; scale folded with LOG2E
    bf16x8 aq[4];
    {
        long base = (long)(b * 2048 + q0 + m32) * 3072 + h * 64;
        float e[32]; float ss = 0.f;
        for (int f = 0; f < 4; ++f) {
            aq[f] = *(const bf16x8*)&qkv[base + f * 16 + half * 8];
            for (int j = 0; j < 8; ++j) { float x = bf2f((unsigned short)aq[f][j]); e[f * 8 + j] = x; ss += x * x; }
        }
        ss += __shfl_xor(ss, 32, 64);
        float rs = (scale * LOG2E) / fmaxf(sqrtf(ss), 1e-12f);
        for (int f = 0; f < 4; ++f)
            for (int j = 0; j < 8; ++j) aq[f][j] = (short)f2bf(e[f * 8 + j] * rs);
    }

    f32x16 o0 = {}, o1 = {}, lacc = {};
    bf16x8 ones; for (int i = 0; i < 8; ++i) ones[i] = (short)0x3F80;
    const int sr = t >> 2, sc = (t & 3) * 16;
    const long kbase = (long)bh * 2048 * 64;
    const long vbase = (long)bh * 64 * 2048;

#define LOADT(kt) \
    kpA = *(const bf16x8*)&kb[kbase + (long)((kt) + sr) * 64 + sc];      \
    kpB = *(const bf16x8*)&kb[kbase + (long)((kt) + sr) * 64 + sc + 8];  \
    vpA = *(const bf16x8*)&vT[vbase + (long)sr * 2048 + (kt) + sc];      \
    vpB = *(const bf16x8*)&vT[vbase + (long)sr * 2048 + (kt) + sc + 8];

#define STORET(buf) \
    *(bf16x8*)&Ks[buf][sr * 72 + sc]     = kpA;  \
    *(bf16x8*)&Ks[buf][sr * 72 + sc + 8] = kpB;  \
    *(bf16x8*)&Vs[buf][sr * 72 + sc]     = vpA;  \
    *(bf16x8*)&Vs[buf][sr * 72 + sc + 8] = vpB;

#define ATTN_STEP(KS, VS, SUB) \
    for (int ktile = 0; ktile < 2; ++ktile) {                                              \
        const unsigned short* krow = &KS[(ktile * 32 + prow) * 72 + half * 8];             \
        f32x16 s = {};                                                                     \
        s = __builtin_amdgcn_mfma_f32_32x32x16_bf16(*(const bf16x8*)&krow[0],  aq[0], s, 0, 0, 0); \
        s = __builtin_amdgcn_mfma_f32_32x32x16_bf16(*(const bf16x8*)&krow[16], aq[1], s, 0, 0, 0); \
        s = __builtin_amdgcn_mfma_f32_32x32x16_bf16(*(const bf16x8*)&krow[32], aq[2], s, 0, 0, 0); \
        s = __builtin_amdgcn_mfma_f32_32x32x16_bf16(*(const bf16x8*)&krow[48], aq[3], s, 0, 0, 0); \
        unsigned pu[16];                                                                   \
        for (int j = 0; j < 16; ++j)                                                       \
            pu[j] = fbits(__builtin_amdgcn_exp2f(s[j] - (SUB)));                           \
        uint4 a0u, a1u;                                                                    \
        a0u.x = __builtin_amdgcn_perm(pu[1],  pu[0],  0x07060302u);                        \
        a0u.y = __builtin_amdgcn_perm(pu[3],  pu[2],  0x07060302u);                        \
        a0u.z = __builtin_amdgcn_perm(pu[5],  pu[4],  0x07060302u);                        \
        a0u.w = __builtin_amdgcn_perm(pu[7],  pu[6],  0x07060302u);                        \
        a1u.x = __builtin_amdgcn_perm(pu[9],  pu[8],  0x07060302u);                        \
        a1u.y = __builtin_amdgcn_perm(pu[11], pu[10], 0x07060302u);                        \
        a1u.z = __builtin_amdgcn_perm(pu[13], pu[12], 0x07060302u);                        \
        a1u.w = __builtin_amdgcn_perm(pu[15], pu[14], 0x07060302u);                        \
        bf16x8 ap0, ap1;                                                                   \
        __builtin_memcpy(&ap0, &a0u, 16); __builtin_memcpy(&ap1, &a1u, 16);                \
        for (int c = 0; c < 2; ++c) {                                                      \
            bf16x8 apc = c ? ap1 : ap0;                                                    \
            bf16x8 bv0 = *(const bf16x8*)&VS[m32 * 72        + ktile * 32 + c * 16 + half * 8]; \
            bf16x8 bv1 = *(const bf16x8*)&VS[(32 + m32) * 72 + ktile * 32 + c * 16 + half * 8]; \
            o0   = __builtin_amdgcn_mfma_f32_32x32x16_bf16(apc, bv0, o0, 0, 0, 0);         \
            o1   = __builtin_amdgcn_mfma_f32_32x32x16_bf16(apc, bv1, o1, 0, 0, 0);         \
            lacc = __builtin_amdgcn_mfma_f32_32x32x16_bf16(apc, ones, lacc, 0, 0, 0);      \
        }                                                                                  \
    }

#define KLOOP(SUB) \
    for (int kt = 0; kt < 2048; kt += 128) {                 \
        LOADT(kt + 64)                                       \
        ATTN_STEP(Ks[0], Vs[0], SUB)                         \
        STORET(1)                                            \
        __syncthreads();                                     \
        const bool more = (kt + 128) < 2048;                 \
        if (more) { LOADT(kt + 128) }                        \
        ATTN_STEP(Ks[1], Vs[1], SUB)                         \
        if (more) {                                          \
            STORET(0)                                        \
            __syncthreads();                                 \
        }                                                    \
    }

    bf16x8 kpA, kpB, vpA, vpB;
    LOADT(0)
    STORET(0)
    __syncthreads();

    if (c2 < 30.0f) {      // wave-uniform; scale=4 here => fast path
        KLOOP(0.0f)        // s - 0.0f folds away: no per-score VALU shift
    } else {
        KLOOP(c2)          // overflow-safe general path
    }
#undef LOADT
#undef STORET
#undef ATTN_STEP
#undef KLOOP

    // epilogue: divide by rowsum (lacc reg r matches o reg r), write attn[B,L,C]
    for (int r = 0; r < 16; ++r) {
        int m = (r & 3) + 8 * (r >> 2) + 4 * half;
        float inv = 1.0f / lacc[r];
        long dst = (long)(b * 2048 + q0 + m) * 1024 + h * 64;
        attn[dst + m32]      = f2bf(o0[r] * inv);
        attn[dst + 32 + m32] = f2bf(o1[r] * inv);
    }
}

// ---------------------------------------------------------------------------
extern "C" void kernel_launch(void* const* d_in, const int* in_sizes, int n_in,
                              void* d_out, int out_size, void* d_ws, size_t ws_size,
                              hipStream_t stream) {
    const float* x    = (const float*)d_in[0];
    const float* Wqkv = (const float*)d_in[1];
    const float* qbia = (const float*)d_in[2];
    const float* vbia = (const float*)d_in[3];
    const float* sml  = (const float*)d_in[4];
    const float* Wp   = (const float*)d_in[5];
    const float* bp   = (const float*)d_in[6];

    char* ws = (char*)d_ws;
    unsigned short* qkv   = (unsigned short*)ws;                    // [0, 50.33MB)
    unsigned short* kbuf  = (unsigned short*)(ws + 50331648);       // hosts Wqkvb first
    unsigned short* Wqkvb = kbuf;
    unsigned short* vT    = (unsigned short*)(ws + 67108864);       // hosts xb first
    unsigned short* xb    = vT;
    unsigned short* attnb = (unsigned short*)(ws + 83886080);
    float*          bias3 = (float*)(ws + 100663296);               // 12KB
    unsigned short* Wpb   = (unsigned short*)(ws + 100679680);      // 2MB
    float*          out   = (float*)d_out;

    hipLaunchKernelGGL(k_prep, dim3(6146), dim3(256), 0, stream,
                       x, Wqkv, Wp, qbia, vbia, xb, Wqkvb, Wpb, bias3);
    hipLaunchKernelGGL((k_gemm_lds<false>), dim3(64, 24), dim3(256), 0, stream,
                       xb, Wqkvb, bias3, (void*)qkv, 3072, 1024);
    hipLaunchKernelGGL(k_prep_kv, dim3(32, 64), dim3(256), 0, stream, qkv, kbuf, vT);
    hipLaunchKernelGGL(k_attn32, dim3(16, 64), dim3(256), 0, stream, qkv, kbuf, vT, sml, attnb);
    hipLaunchKernelGGL((k_gemm_lds<true>), dim3(64, 8), dim3(256), 0, stream,
                       attnb, Wpb, bp, (void*)out, 1024, 1024);
}